// Round 4
// baseline (18998.526 us; speedup 1.0000x reference)
//
#include <hip/hip_runtime.h>
#include <math.h>

#define D_  1024
#define S_  2048
#define B_  2
#define M_  (B_*S_)      // 4096 tokens
#define H_  16
#define HD_ 64
#define V_  32768
#define HM_ 4096
#define LG_ 8
#define NC_ (S_/64)      // 32 chunks
#define NS_ 16           // vocab slices for LM head
#define HCOLS (V_/NS_)   // 2048 cols per slice

#define GBM 128
#define GBN 128
#define GBK 16
#define LDP 132          // padded LDS leading dim (mult of 4 for float4, +4 breaks bank stride)

__device__ __forceinline__ float sigmoidf_(float x) { return 1.f / (1.f + expf(-x)); }

// ---------------- embedding gather ----------------
__global__ __launch_bounds__(256) void embed_k(const int* __restrict__ ids,
    const float* __restrict__ emb, float* __restrict__ x) {
  int row = blockIdx.x;
  int id = ids[row];
  const float4* s = (const float4*)(emb + (size_t)id * D_);
  float4* d = (float4*)(x + (size_t)row * D_);
  d[threadIdx.x] = s[threadIdx.x];
}

// ---------------- rmsnorm (D=1024, weighted) ----------------
__global__ __launch_bounds__(256) void rmsnorm_k(const float* __restrict__ in,
    const float* __restrict__ w, float* __restrict__ out, float eps) {
  int row = blockIdx.x, tid = threadIdx.x;
  float4 v = ((const float4*)(in + (size_t)row * D_))[tid];
  float ss = v.x*v.x + v.y*v.y + v.z*v.z + v.w*v.w;
  #pragma unroll
  for (int d = 1; d < 64; d <<= 1) ss += __shfl_xor(ss, d);
  __shared__ float red[4];
  if ((tid & 63) == 0) red[tid >> 6] = ss;
  __syncthreads();
  float tot = red[0] + red[1] + red[2] + red[3];
  float r = rsqrtf(tot * (1.f / D_) + eps);
  float4 wv = ((const float4*)w)[tid];
  float4 o;
  o.x = v.x * r * wv.x; o.y = v.y * r * wv.y;
  o.z = v.z * r * wv.z; o.w = v.w * r * wv.w;
  ((float4*)(out + (size_t)row * D_))[tid] = o;
}

// ---------------- fp32 GEMM: C[m,n] = sum_k A[m,k]*W[n,k]  (+ epilogue) ----------------
// EPI: 0 = none, 1 = silu, 2 = res + rsc*val.
// NOTE: C and res are NOT __restrict__ — they alias (x) in the EPI=2 residual path.
template <int EPI>
__global__ __launch_bounds__(256) void gemm_k(const float* __restrict__ A,
    const float* __restrict__ W, float* C,
    const float* res, int N, int K, float rsc) {
  __shared__ float As[GBK][LDP];
  __shared__ float Bs[GBK][LDP];
  int bn = blockIdx.x, bm = blockIdx.y;
  int tid = threadIdx.x;
  int tx = tid & 15, ty = tid >> 4;
  const float* Ab = A + (size_t)bm * GBM * K;
  const float* Wb = W + (size_t)bn * GBN * K;
  float acc[2][2][4][4] = {};
  #pragma unroll 1
  for (int k0 = 0; k0 < K; k0 += GBK) {
    #pragma unroll
    for (int i = 0; i < 2; i++) {
      int idx = tid + i * 256;          // 0..511
      int r = idx >> 2, c4 = idx & 3;   // 128 rows x 4 float4
      float4 va = *(const float4*)(Ab + (size_t)r * K + k0 + c4 * 4);
      As[c4*4+0][r] = va.x; As[c4*4+1][r] = va.y; As[c4*4+2][r] = va.z; As[c4*4+3][r] = va.w;
      float4 vb = *(const float4*)(Wb + (size_t)r * K + k0 + c4 * 4);
      Bs[c4*4+0][r] = vb.x; Bs[c4*4+1][r] = vb.y; Bs[c4*4+2][r] = vb.z; Bs[c4*4+3][r] = vb.w;
    }
    __syncthreads();
    #pragma unroll
    for (int kk = 0; kk < GBK; kk++) {
      float a[2][4], b[2][4];
      *(float4*)a[0] = *(const float4*)&As[kk][ty * 4];
      *(float4*)a[1] = *(const float4*)&As[kk][64 + ty * 4];
      *(float4*)b[0] = *(const float4*)&Bs[kk][tx * 4];
      *(float4*)b[1] = *(const float4*)&Bs[kk][64 + tx * 4];
      #pragma unroll
      for (int hr = 0; hr < 2; hr++)
        #pragma unroll
        for (int i = 0; i < 4; i++)
          #pragma unroll
          for (int hc = 0; hc < 2; hc++)
            #pragma unroll
            for (int j = 0; j < 4; j++)
              acc[hr][hc][i][j] = fmaf(a[hr][i], b[hc][j], acc[hr][hc][i][j]);
    }
    __syncthreads();
  }
  #pragma unroll
  for (int hr = 0; hr < 2; hr++)
    #pragma unroll
    for (int i = 0; i < 4; i++) {
      size_t row = (size_t)bm * GBM + hr * 64 + ty * 4 + i;
      #pragma unroll
      for (int hc = 0; hc < 2; hc++) {
        size_t col = (size_t)bn * GBN + hc * 64 + tx * 4;
        float v[4];
        #pragma unroll
        for (int j = 0; j < 4; j++) {
          float t = acc[hr][hc][i][j];
          if (EPI == 1) t = t * (1.f / (1.f + expf(-t)));   // silu
          v[j] = t;
        }
        float* cp = C + row * (size_t)N + col;
        if (EPI == 2) {
          float4 rv = *(const float4*)(res + row * (size_t)N + col);
          v[0] = rv.x + rsc * v[0]; v[1] = rv.y + rsc * v[1];
          v[2] = rv.z + rsc * v[2]; v[3] = rv.w + rsc * v[3];
        }
        float4 o; o.x = v[0]; o.y = v[1]; o.z = v[2]; o.w = v[3];
        *(float4*)cp = o;
      }
    }
}

// ---------------- GDN pointwise: q-rms / tanh*v -> u / sigmoid-clip a / sigmoid g ----------------
__global__ __launch_bounds__(256) void gdn_pw_k(float* __restrict__ proj) {
  int row = blockIdx.x, tid = threadIdx.x;
  float* p = proj + (size_t)row * (5 * D_);
  // q: per-head (64) rms, 16 lanes/head x 4 elems
  int h = tid >> 4, sub = tid & 15;
  float4 q = *(float4*)(p + h * 64 + sub * 4);
  float ss = q.x*q.x + q.y*q.y + q.z*q.z + q.w*q.w;
  #pragma unroll
  for (int d = 1; d < 16; d <<= 1) ss += __shfl_xor(ss, d, 16);
  float r = rsqrtf(ss * (1.f / 64.f) + 1.1920929e-07f);
  q.x *= r; q.y *= r; q.z *= r; q.w *= r;
  *(float4*)(p + h * 64 + sub * 4) = q;
  // k,v -> u (into k region); a; g : 4 elems each
  int d0 = tid * 4;
  float4 k4 = *(float4*)(p + D_ + d0);
  float4 v4 = *(float4*)(p + 2 * D_ + d0);
  float4 u;
  u.x = tanhf(k4.x) * v4.x; u.y = tanhf(k4.y) * v4.y;
  u.z = tanhf(k4.z) * v4.z; u.w = tanhf(k4.w) * v4.w;
  *(float4*)(p + D_ + d0) = u;
  float4 a4 = *(float4*)(p + 3 * D_ + d0);
  a4.x = fminf(fmaxf(sigmoidf_(a4.x + 2.f), 0.6f), 0.9995f);
  a4.y = fminf(fmaxf(sigmoidf_(a4.y + 2.f), 0.6f), 0.9995f);
  a4.z = fminf(fmaxf(sigmoidf_(a4.z + 2.f), 0.6f), 0.9995f);
  a4.w = fminf(fmaxf(sigmoidf_(a4.w + 2.f), 0.6f), 0.9995f);
  *(float4*)(p + 3 * D_ + d0) = a4;
  float4 g4 = *(float4*)(p + 4 * D_ + d0);
  g4.x = sigmoidf_(g4.x); g4.y = sigmoidf_(g4.y);
  g4.z = sigmoidf_(g4.z); g4.w = sigmoidf_(g4.w);
  *(float4*)(p + 4 * D_ + d0) = g4;
}

// ---------------- GDN chunk-parallel scan (3 phases, exact reference arithmetic) ----------------
// state_c = P_c*(state_{c-1} + A_c); P_c = prod(a), A_c = sum(u / max(prefix,1e-6)).

// phase 1: grid (NC_, B_*H_), block 64 (one thread per e)
__global__ __launch_bounds__(64) void gdn_scan_p1(const float* __restrict__ proj,
    float* __restrict__ Pc, float* __restrict__ Ac) {
  int c = blockIdx.x, bh = blockIdx.y;
  int b = bh >> 4, h = bh & 15;
  int e = threadIdx.x;
  const float* base = proj + ((size_t)(b * S_ + c * 64)) * (5 * D_) + h * 64 + e;
  float p = 1.f, acc = 0.f;
  #pragma unroll 8
  for (int t = 0; t < 64; t++) {
    float a = base[(size_t)t * (5 * D_) + 3 * D_];
    float u = base[(size_t)t * (5 * D_) + D_];
    p *= a;
    acc += u / fmaxf(p, 1e-6f);
  }
  size_t idx = ((size_t)bh * NC_ + c) * 64 + e;
  Pc[idx] = p; Ac[idx] = acc;
}

// phase 2: grid B_*H_, block 64; per (b,h,e) scan 32 chunks
__global__ __launch_bounds__(64) void gdn_scan_p2(const float* __restrict__ Pc,
    const float* __restrict__ Ac, float* __restrict__ carry) {
  int bh = blockIdx.x, e = threadIdx.x;
  float state = 0.f;
  for (int c = 0; c < NC_; c++) {
    size_t idx = ((size_t)bh * NC_ + c) * 64 + e;
    carry[idx] = state;
    state = Pc[idx] * (state + Ac[idx]);   // same op order as reference
  }
}

// phase 3: grid (NC_, B_*H_), block 64
__global__ __launch_bounds__(64) void gdn_scan_p3(const float* __restrict__ proj,
    const float* __restrict__ carry, float* __restrict__ mem) {
  int c = blockIdx.x, bh = blockIdx.y;
  int b = bh >> 4, h = bh & 15;
  int e = threadIdx.x;
  const float* base = proj + ((size_t)(b * S_ + c * 64)) * (5 * D_) + h * 64 + e;
  float* wp = mem + ((size_t)(b * S_ + c * 64)) * D_ + h * 64 + e;
  float st = carry[((size_t)bh * NC_ + c) * 64 + e];
  float p = 1.f, acc = 0.f;
  #pragma unroll 8
  for (int t = 0; t < 64; t++) {
    float a = base[(size_t)t * (5 * D_) + 3 * D_];
    float u = base[(size_t)t * (5 * D_) + D_];
    p *= a;
    acc += u / fmaxf(p, 1e-6f);
    wp[(size_t)t * D_] = p * (st + acc);
  }
}

// ---------------- GDN output mix: y = g*(q*mem) + (1-g)*v  (in-place into mem) ----------------
__global__ __launch_bounds__(256) void gdn_y_k(const float* __restrict__ proj,
                                               float* __restrict__ mem) {
  size_t idx = (size_t)blockIdx.x * 256 + threadIdx.x;  // float4 index over M_*D_/4
  size_t row = idx >> 8;
  int d4 = (int)(idx & 255);
  const float* p = proj + row * (5 * D_);
  float4 q = *(const float4*)(p + d4 * 4);
  float4 v = *(const float4*)(p + 2 * D_ + d4 * 4);
  float4 g = *(const float4*)(p + 4 * D_ + d4 * 4);
  float4 m = *(const float4*)(mem + idx * 4);
  float4 o;
  o.x = g.x * (q.x * m.x) + (1.f - g.x) * v.x;
  o.y = g.y * (q.y * m.y) + (1.f - g.y) * v.y;
  o.z = g.z * (q.z * m.z) + (1.f - g.z) * v.z;
  o.w = g.w * (q.w * m.w) + (1.f - g.w) * v.w;
  *(float4*)(mem + idx * 4) = o;
}

// ---------------- flash attention (fp32, hd=64, causal) ----------------
__global__ __launch_bounds__(256) void attn_k(const float* __restrict__ qkv,
                                              float* __restrict__ out) {
  int qt = blockIdx.x;            // 0..7 (256 q rows each)
  int bh = blockIdx.y;            // b*16+h
  int b = bh >> 4, h = bh & 15;
  int tid = threadIdx.x;
  int s = qt * 256 + tid;
  const float* qrow = qkv + ((size_t)(b * S_ + s)) * (3 * D_) + h * 64;
  float q[64];
  #pragma unroll
  for (int e = 0; e < 64; e += 4) {
    float4 t = *(const float4*)(qrow + e);
    q[e] = t.x * 0.125f; q[e+1] = t.y * 0.125f; q[e+2] = t.z * 0.125f; q[e+3] = t.w * 0.125f;
  }
  __shared__ float Ks[64][64];
  __shared__ float Vs[64][64];
  float m = -3.0e38f, l = 0.f;
  float acc[64];
  #pragma unroll
  for (int e = 0; e < 64; e++) acc[e] = 0.f;
  int nkt = qt * 4 + 4;
  #pragma unroll 1
  for (int kt = 0; kt < nkt; kt++) {
    __syncthreads();
    #pragma unroll
    for (int i = 0; i < 4; i++) {
      int idx = tid + i * 256;        // 0..1023
      int r = idx >> 4, c4 = idx & 15;
      size_t krow = ((size_t)(b * S_ + kt * 64 + r)) * (3 * D_) + h * 64;
      *(float4*)(&Ks[r][c4 * 4]) = *(const float4*)(qkv + krow + D_ + c4 * 4);
      *(float4*)(&Vs[r][c4 * 4]) = *(const float4*)(qkv + krow + 2 * D_ + c4 * 4);
    }
    __syncthreads();
    int jmax = s - kt * 64 + 1;
    if (jmax > 64) jmax = 64;
    #pragma unroll 1
    for (int j = 0; j < jmax; j++) {
      float sc = 0.f;
      #pragma unroll
      for (int e4 = 0; e4 < 16; e4++) {
        float4 kv = *(const float4*)(&Ks[j][e4 * 4]);
        sc = fmaf(q[e4*4], kv.x, sc); sc = fmaf(q[e4*4+1], kv.y, sc);
        sc = fmaf(q[e4*4+2], kv.z, sc); sc = fmaf(q[e4*4+3], kv.w, sc);
      }
      if (sc > m) {
        float scale = expf(m - sc);
        l *= scale;
        #pragma unroll
        for (int e = 0; e < 64; e++) acc[e] *= scale;
        m = sc;
      }
      float pw = expf(sc - m);
      l += pw;
      #pragma unroll
      for (int e4 = 0; e4 < 16; e4++) {
        float4 vv = *(const float4*)(&Vs[j][e4 * 4]);
        acc[e4*4]   = fmaf(pw, vv.x, acc[e4*4]);
        acc[e4*4+1] = fmaf(pw, vv.y, acc[e4*4+1]);
        acc[e4*4+2] = fmaf(pw, vv.z, acc[e4*4+2]);
        acc[e4*4+3] = fmaf(pw, vv.w, acc[e4*4+3]);
      }
    }
  }
  float inv = 1.f / l;
  float* orow = out + ((size_t)(b * S_ + s)) * D_ + h * 64;
  #pragma unroll
  for (int e = 0; e < 64; e += 4) {
    float4 o; o.x = acc[e] * inv; o.y = acc[e+1] * inv; o.z = acc[e+2] * inv; o.w = acc[e+3] * inv;
    *(float4*)(orow + e) = o;
  }
}

// ---------------- LM head: per (token-tile, vocab-slice) online max/sumexp ----------------
__global__ __launch_bounds__(256) void head_partial_k(const float* __restrict__ xn,
    const float* __restrict__ emb, const float* __restrict__ bias,
    float* __restrict__ part_m, float* __restrict__ part_l) {
  __shared__ float As[GBK][LDP];
  __shared__ float Bs[GBK][LDP];
  int slice = blockIdx.x, bm = blockIdx.y;
  int tid = threadIdx.x, tx = tid & 15, ty = tid >> 4;
  const float* Ab = xn + (size_t)bm * GBM * D_;
  float m_run[2][4], l_run[2][4];
  #pragma unroll
  for (int hr = 0; hr < 2; hr++)
    #pragma unroll
    for (int i = 0; i < 4; i++) { m_run[hr][i] = -3.0e38f; l_run[hr][i] = 0.f; }
  #pragma unroll 1
  for (int cb = 0; cb < HCOLS; cb += GBN) {
    int col0 = slice * HCOLS + cb;
    const float* Wb = emb + (size_t)col0 * D_;
    float acc[2][2][4][4] = {};
    #pragma unroll 1
    for (int k0 = 0; k0 < D_; k0 += GBK) {
      #pragma unroll
      for (int i = 0; i < 2; i++) {
        int idx = tid + i * 256;
        int r = idx >> 2, c4 = idx & 3;
        float4 va = *(const float4*)(Ab + (size_t)r * D_ + k0 + c4 * 4);
        As[c4*4+0][r] = va.x; As[c4*4+1][r] = va.y; As[c4*4+2][r] = va.z; As[c4*4+3][r] = va.w;
        float4 vb = *(const float4*)(Wb + (size_t)r * D_ + k0 + c4 * 4);
        Bs[c4*4+0][r] = vb.x; Bs[c4*4+1][r] = vb.y; Bs[c4*4+2][r] = vb.z; Bs[c4*4+3][r] = vb.w;
      }
      __syncthreads();
      #pragma unroll
      for (int kk = 0; kk < GBK; kk++) {
        float a[2][4], b[2][4];
        *(float4*)a[0] = *(const float4*)&As[kk][ty * 4];
        *(float4*)a[1] = *(const float4*)&As[kk][64 + ty * 4];
        *(float4*)b[0] = *(const float4*)&Bs[kk][tx * 4];
        *(float4*)b[1] = *(const float4*)&Bs[kk][64 + tx * 4];
        #pragma unroll
        for (int hr = 0; hr < 2; hr++)
          #pragma unroll
          for (int i = 0; i < 4; i++)
            #pragma unroll
            for (int hc = 0; hc < 2; hc++)
              #pragma unroll
              for (int j = 0; j < 4; j++)
                acc[hr][hc][i][j] = fmaf(a[hr][i], b[hc][j], acc[hr][hc][i][j]);
      }
      __syncthreads();
    }
    float bb[2][4];
    #pragma unroll
    for (int hc = 0; hc < 2; hc++)
      #pragma unroll
      for (int j = 0; j < 4; j++)
        bb[hc][j] = bias[col0 + hc * 64 + tx * 4 + j];
    #pragma unroll
    for (int hr = 0; hr < 2; hr++)
      #pragma unroll
      for (int i = 0; i < 4; i++) {
        float tm = -3.0e38f;
        #pragma unroll
        for (int hc = 0; hc < 2; hc++)
          #pragma unroll
          for (int j = 0; j < 4; j++)
            tm = fmaxf(tm, acc[hr][hc][i][j] + bb[hc][j]);
        #pragma unroll
        for (int d = 1; d < 16; d <<= 1) tm = fmaxf(tm, __shfl_xor(tm, d, 16));
        float nm = fmaxf(m_run[hr][i], tm);
        float ls = 0.f;
        #pragma unroll
        for (int hc = 0; hc < 2; hc++)
          #pragma unroll
          for (int j = 0; j < 4; j++)
            ls += expf(acc[hr][hc][i][j] + bb[hc][j] - nm);
        #pragma unroll
        for (int d = 1; d < 16; d <<= 1) ls += __shfl_xor(ls, d, 16);
        l_run[hr][i] = l_run[hr][i] * expf(m_run[hr][i] - nm) + ls;
        m_run[hr][i] = nm;
      }
  }
  if (tx == 0) {
    #pragma unroll
    for (int hr = 0; hr < 2; hr++)
      #pragma unroll
      for (int i = 0; i < 4; i++) {
        int row = bm * GBM + hr * 64 + ty * 4 + i;
        part_m[slice * M_ + row] = m_run[hr][i];
        part_l[slice * M_ + row] = l_run[hr][i];
      }
  }
}

// ---------------- target logit: dot(xn[row], emb[tgt[row]]) + bias[tgt] ----------------
__global__ __launch_bounds__(256) void tlogit_k(const float* __restrict__ xn,
    const float* __restrict__ emb, const float* __restrict__ bias,
    const int* __restrict__ tgt, float* __restrict__ tl) {
  int row = blockIdx.x, tid = threadIdx.x;
  int t = tgt[row];
  float4 a = ((const float4*)(xn + (size_t)row * D_))[tid];
  float4 b = ((const float4*)(emb + (size_t)t * D_))[tid];
  float s = a.x*b.x + a.y*b.y + a.z*b.z + a.w*b.w;
  #pragma unroll
  for (int d = 1; d < 64; d <<= 1) s += __shfl_xor(s, d);
  __shared__ float red[4];
  if ((tid & 63) == 0) red[tid >> 6] = s;
  __syncthreads();
  if (tid == 0) tl[row] = red[0] + red[1] + red[2] + red[3] + bias[t];
}

// ---------------- finalize: merge slices, mean NLL ----------------
__global__ __launch_bounds__(1024) void final_k(const float* __restrict__ pm,
    const float* __restrict__ pl, const float* __restrict__ tl, float* __restrict__ out) {
  int tid = threadIdx.x;
  float sum = 0.f;
  for (int t = tid; t < M_; t += 1024) {
    float mx = -3.0e38f;
    #pragma unroll
    for (int s = 0; s < NS_; s++) mx = fmaxf(mx, pm[s * M_ + t]);
    float L = 0.f;
    #pragma unroll
    for (int s = 0; s < NS_; s++) L += pl[s * M_ + t] * expf(pm[s * M_ + t] - mx);
    sum += mx + logf(L) - tl[t];
  }
  #pragma unroll
  for (int d = 1; d < 64; d <<= 1) sum += __shfl_xor(sum, d);
  __shared__ float red[16];
  if ((tid & 63) == 0) red[tid >> 6] = sum;
  __syncthreads();
  if (tid < 16) {
    float s2 = red[tid];
    #pragma unroll
    for (int d = 1; d < 16; d <<= 1) s2 += __shfl_xor(s2, d, 16);
    if (tid == 0) out[0] = s2 * (1.f / (float)M_);
  }
}

// ---------------- orchestration ----------------
// Workspace plan (peak ~113.3 MB):
//   x    [M,D]   16 MB   residual stream
//   xnm  [M,D]   16 MB   rmsnorm output; REUSED as GDN memory / y and attn output
//                        (xn is dead once the projection GEMM reading it completes,
//                         which is stream-ordered before any aliased write)
//   big  [M,5D]  80 MB   GDN proj / MLP hidden / attn qkv
//   pm,pl,tl, Pc,Ac,cry  ~1.3 MB
extern "C" void kernel_launch(void* const* d_in, const int* in_sizes, int n_in,
                              void* d_out, int out_size, void* d_ws, size_t ws_size,
                              hipStream_t stream) {
  (void)in_sizes; (void)n_in; (void)out_size; (void)ws_size;
  const int*   ids  = (const int*)d_in[0];
  const int*   tgt  = (const int*)d_in[1];
  const float* emb  = (const float*)d_in[2];
  const float* bias = (const float*)d_in[3];
  const float* gin  = (const float*)d_in[4];
  const float* gout = (const float*)d_in[5];
  const float* gn1  = (const float*)d_in[6];
  const float* gn2  = (const float*)d_in[7];
  const float* gfc  = (const float*)d_in[8];
  const float* gpj  = (const float*)d_in[9];
  const float* aqkv = (const float*)d_in[10];
  const float* apj  = (const float*)d_in[11];
  const float* an1  = (const float*)d_in[12];
  const float* an2  = (const float*)d_in[13];
  const float* afc  = (const float*)d_in[14];
  const float* ampj = (const float*)d_in[15];
  const float* fnw  = (const float*)d_in[16];

  float* ws  = (float*)d_ws;
  float* x   = ws;                               // [M, D]
  float* xnm = x   + (size_t)M_ * D_;            // [M, D]  norm out / mem / y / attn out
  float* big = xnm + (size_t)M_ * D_;            // [M, 5D]
  float* pm  = big + (size_t)M_ * 5 * D_;        // [NS, M]
  float* pl  = pm  + (size_t)NS_ * M_;           // [NS, M]
  float* tl  = pl  + (size_t)NS_ * M_;           // [M]
  float* Pc  = tl  + (size_t)M_;                 // [BH, NC, 64]
  float* Ac  = Pc  + (size_t)B_ * H_ * NC_ * 64; // [BH, NC, 64]
  float* cry = Ac  + (size_t)B_ * H_ * NC_ * 64; // [BH, NC, 64]

  dim3 blk(256);
  embed_k<<<M_, blk, 0, stream>>>(ids, emb, x);

  for (int i = 0; i < LG_; i++) {
    float rsc = (float)(1.0 / sqrt(2.0 * (i + 1)));
    // mixer
    rmsnorm_k<<<M_, blk, 0, stream>>>(x, gn1 + (size_t)i * D_, xnm, 1e-6f);
    gemm_k<0><<<dim3(5 * D_ / GBN, M_ / GBM), blk, 0, stream>>>(
        xnm, gin + (size_t)i * 5 * D_ * D_, big, nullptr, 5 * D_, D_, 0.f);
    gdn_pw_k<<<M_, blk, 0, stream>>>(big);
    gdn_scan_p1<<<dim3(NC_, B_ * H_), dim3(64), 0, stream>>>(big, Pc, Ac);
    gdn_scan_p2<<<B_ * H_, dim3(64), 0, stream>>>(Pc, Ac, cry);
    gdn_scan_p3<<<dim3(NC_, B_ * H_), dim3(64), 0, stream>>>(big, cry, xnm);  // xn dead -> mem
    gdn_y_k<<<M_, blk, 0, stream>>>(big, xnm);
    gemm_k<2><<<dim3(D_ / GBN, M_ / GBM), blk, 0, stream>>>(
        xnm, gout + (size_t)i * D_ * D_, x, x, D_, D_, rsc);
    // mlp
    rmsnorm_k<<<M_, blk, 0, stream>>>(x, gn2 + (size_t)i * D_, xnm, 1e-6f);
    gemm_k<1><<<dim3(HM_ / GBN, M_ / GBM), blk, 0, stream>>>(
        xnm, gfc + (size_t)i * HM_ * D_, big, nullptr, HM_, D_, 0.f);
    gemm_k<2><<<dim3(D_ / GBN, M_ / GBM), blk, 0, stream>>>(
        big, gpj + (size_t)i * D_ * HM_, x, x, D_, HM_, rsc);
  }

  float rsc9 = (float)(1.0 / sqrt(2.0 * (LG_ + 1)));
  // attention block
  rmsnorm_k<<<M_, blk, 0, stream>>>(x, an1, xnm, 1e-6f);
  gemm_k<0><<<dim3(3 * D_ / GBN, M_ / GBM), blk, 0, stream>>>(
      xnm, aqkv, big, nullptr, 3 * D_, D_, 0.f);
  attn_k<<<dim3(S_ / 256, B_ * H_), blk, 0, stream>>>(big, xnm);  // xn dead -> attn out
  gemm_k<2><<<dim3(D_ / GBN, M_ / GBM), blk, 0, stream>>>(
      xnm, apj, x, x, D_, D_, rsc9);
  rmsnorm_k<<<M_, blk, 0, stream>>>(x, an2, xnm, 1e-6f);
  gemm_k<1><<<dim3(HM_ / GBN, M_ / GBM), blk, 0, stream>>>(
      xnm, afc, big, nullptr, HM_, D_, 0.f);
  gemm_k<2><<<dim3(D_ / GBN, M_ / GBM), blk, 0, stream>>>(
      big, ampj, x, x, D_, HM_, rsc9);

  // head
  rmsnorm_k<<<M_, blk, 0, stream>>>(x, fnw, xnm, 1e-6f);
  head_partial_k<<<dim3(NS_, M_ / GBM), blk, 0, stream>>>(xnm, emb, bias, pm, pl);
  tlogit_k<<<M_, blk, 0, stream>>>(xnm, emb, bias, tgt, tl);
  final_k<<<1, dim3(1024), 0, stream>>>(pm, pl, tl, (float*)d_out);
}